// Round 25
// baseline (43.744 us; speedup 1.0000x reference)
//
#include <hip/hip_runtime.h>
#include <math.h>

#define N 2048
#define D 48
#define K 16
#define TILE 32
#define NT (N / TILE)              // 64 tiles per dimension
#define NBLK (NT * (NT + 1) / 2)   // 2080 upper-triangular tiles
#define ROWF 52                    // padded raw-row floats
#define RAWSET (TILE * ROWF)

// F-PROBE ROUND: exact r23 kernel, launched TWICE on the stream.
// M = F_graph + 2*(C + F_disp); r23 single = 24.4 = F_graph + C + F_disp.
// M ~ 38-40  => ~10us fixed graph overhead (kernels near true floor)
// M ~ 47-50  => overhead ~0, the 24us is real work (attack LDS ratio next)
//
// FROZEN numerics contract (validated r18, absmax = 1 bf16 ulp):
//   s = (q0 + q2) + q1 (plain, pinned); g = fma(x2,y2, fma(x1,y1, fl(x0*y0)))
//   t1 = fl(s_n + s_m); d2 = fmaf(-2,g,t1); dist = sqrt(fmax(d2,0))

__global__ __launch_bounds__(128, 4)
void volt_tri(const float* __restrict__ vct, const float* __restrict__ posnum,
              float* __restrict__ out) {
#pragma clang fp contract(off)
    __shared__ float4 AB[2][K * TILE];
    float* Raw = reinterpret_cast<float*>(AB);
    float* T   = reinterpret_cast<float*>(AB);

    const int tid = threadIdx.x;

    int t = blockIdx.x;
    int by = 0;
    while ((by + 1) * NT - ((by + 1) * by) / 2 <= t) ++by;
    const int bx = by + (t - (by * NT - (by * (by - 1)) / 2));

    const int row0 = by * TILE, col0 = bx * TILE;

    const float tau = posnum[0];
    const float lam = posnum[1];
    const float t2 = tau * tau;
    const float l2 = lam * lam;

#pragma unroll
    for (int it = 0; it < 6; ++it) {
        int task = tid + 128 * it;
        int set = task / 384;
        int rem = task - set * 384;
        int r = rem / 12;
        int c4 = rem - r * 12;
        const float4 v = *reinterpret_cast<const float4*>(
            &vct[((set ? col0 : row0) + r) * D + c4 * 4]);
        *reinterpret_cast<float4*>(&Raw[set * RAWSET + r * ROWF + c4 * 4]) = v;
    }
    __syncthreads();

    float rx0[8], rx1[8], rx2[8], rs[8];
#pragma unroll
    for (int it = 0; it < 8; ++it) {
        int task = tid + 128 * it;
        int set = task >> 9;
        int rk = task & 511;
        int r = rk & 31, k = rk >> 5;
        int base = set * RAWSET + r * ROWF + 3 * k;
        float x0 = Raw[base + 0];
        float x1 = Raw[base + 1];
        float x2 = Raw[base + 2];
        float q0 = x0 * x0, q1 = x1 * x1, q2 = x2 * x2;
        asm volatile("" : "+v"(q0), "+v"(q1), "+v"(q2));
        float s02 = q0 + q2;
        asm volatile("" : "+v"(s02));
        rs[it] = s02 + q1;
        rx0[it] = x0; rx1[it] = x1; rx2[it] = x2;
    }
    __syncthreads();

#pragma unroll
    for (int it = 0; it < 8; ++it) {
        int task = tid + 128 * it;
        int set = task >> 9;
        int rk = task & 511;
        int r = rk & 31, k = rk >> 5;
        AB[set][k * TILE + r] = make_float4(rx0[it], rx1[it], rx2[it], rs[it]);
    }
    __syncthreads();

    const int tx = tid & 15;
    const int ty = tid >> 4;

    float G[4][2], Pd[4][2];
#pragma unroll
    for (int i = 0; i < 4; ++i)
#pragma unroll
        for (int j = 0; j < 2; ++j) { G[i][j] = 0.0f; Pd[i][j] = 1.0f; }

#pragma unroll
    for (int k = K - 1; k >= 0; --k) {
        float4 a[4], b[2];
#pragma unroll
        for (int i = 0; i < 4; ++i) a[i] = AB[0][k * TILE + ty + 8 * i];
#pragma unroll
        for (int j = 0; j < 2; ++j) b[j] = AB[1][k * TILE + tx + 16 * j];
#pragma unroll
        for (int i = 0; i < 4; ++i)
#pragma unroll
            for (int j = 0; j < 2; ++j) {
                float g = __builtin_fmaf(a[i].z, b[j].z,
                          __builtin_fmaf(a[i].y, b[j].y, a[i].x * b[j].x));
                float t1 = a[i].w + b[j].w;
                float d2 = __builtin_fmaf(-2.0f, g, t1);
                float dist = __builtin_amdgcn_sqrtf(fmaxf(d2, 0.0f));
                float ip  = 1.0f - dist;
                float den = 1.0f - t2 * ip;
                G[i][j]  = l2 * (Pd[i][j] + G[i][j]);
                Pd[i][j] = Pd[i][j] * den;
            }
    }

    float val[4][2];
#pragma unroll
    for (int i = 0; i < 4; ++i)
#pragma unroll
        for (int j = 0; j < 2; ++j)
            val[i][j] = 1.0f + G[i][j] * __builtin_amdgcn_rcpf(Pd[i][j]);

#pragma unroll
    for (int i = 0; i < 4; ++i) {
        int r = ty + 8 * i;
#pragma unroll
        for (int j = 0; j < 2; ++j)
            out[(size_t)(row0 + r) * N + (col0 + tx + 16 * j)] = val[i][j];
    }

    if (bx != by) {
        __syncthreads();
#pragma unroll
        for (int i = 0; i < 4; ++i)
#pragma unroll
            for (int j = 0; j < 2; ++j)
                T[(tx + 16 * j) * 33 + (ty + 8 * i)] = val[i][j];
        __syncthreads();
#pragma unroll
        for (int i = 0; i < 4; ++i) {
            int rr = ty + 8 * i;
#pragma unroll
            for (int j = 0; j < 2; ++j) {
                int cc = tx + 16 * j;
                out[(size_t)(col0 + rr) * N + (row0 + cc)] = T[rr * 33 + cc];
            }
        }
    }
}

extern "C" void kernel_launch(void* const* d_in, const int* in_sizes, int n_in,
                              void* d_out, int out_size, void* d_ws, size_t ws_size,
                              hipStream_t stream) {
    const float* vct    = (const float*)d_in[0];
    const float* posnum = (const float*)d_in[1];
    float* out          = (float*)d_out;

    // F-probe: identical kernel twice (idempotent, deterministic).
    volt_tri<<<NBLK, 128, 0, stream>>>(vct, posnum, out);
    volt_tri<<<NBLK, 128, 0, stream>>>(vct, posnum, out);
}

// Round 26
// 26.804 us; speedup vs baseline: 1.6320x; 1.6320x over previous
//
#include <hip/hip_runtime.h>
#include <math.h>

#define N 2048
#define D 48
#define K 16
#define TILE 32
#define NT (N / TILE)              // 64 tiles per dimension
#define NBLK (NT * (NT + 1) / 2)   // 2080 upper-triangular tiles
#define ROWF 52                    // padded raw-row floats (16B-aligned rows)
#define RAWSET (TILE * ROWF)
#define ST 36                      // mirror-transpose stride (<=2-way alias)

// FROZEN numerics contract (validated r18, absmax = 1 bf16 ulp):
//   s = (q0 + q2) + q1 (plain, pinned); g = fma(x2,y2, fma(x1,y1, fl(x0*y0)))
//   t1 = fl(s_n + s_m); d2 = fmaf(-2,g,t1); dist = sqrt(fmax(d2,0))
// den = fmaf(t2, dist, 1-t2): downstream-only rewrite, dev <= 4e-5 (safe).
// r25 probe: F ~ 5us fixed, C ~ 19.3us real work; corrected budget showed
// LDS 10.8 + VALU 7.6 + HBM 3 serialize. This round: 64-thr 4x4 micro
// (0.5 LDS reads/pair) + coalesced staging (r24 minus its confounds) + den-fma.

__global__ __launch_bounds__(64, 2)
void volt_tri(const float* __restrict__ vct, const float* __restrict__ posnum,
              float* __restrict__ out) {
#pragma clang fp contract(off)
    __shared__ float4 AB[2][K * TILE];            // 16 KB -> 10 blocks/CU
    float* Raw = reinterpret_cast<float*>(AB);    // aliased (13 KB)
    float* T   = reinterpret_cast<float*>(AB);    // aliased mirror transpose

    const int lane = threadIdx.x;

    // decode upper-triangular tile (by <= bx)
    int t = blockIdx.x;
    int by = 0;
    while ((by + 1) * NT - ((by + 1) * by) / 2 <= t) ++by;
    const int bx = by + (t - (by * NT - (by * (by - 1)) / 2));
    const int row0 = by * TILE, col0 = bx * TILE;

    const float tau = posnum[0];
    const float lam = posnum[1];
    const float t2 = tau * tau;     // fl(tau^2)
    const float l2 = lam * lam;     // fl(lam^2)
    const float c0 = 1.0f - t2;     // hoisted for den-fma

    // ---- phase 1: coalesced float4 loads of both 32x48 tiles ----
#pragma unroll
    for (int it = 0; it < 6; ++it) {
        int task = lane + 64 * it;            // 0..383
        int r = task / 12;                    // magic-mul, cheap
        int c4 = task - r * 12;
        const float4 v = *reinterpret_cast<const float4*>(
            &vct[(row0 + r) * D + c4 * 4]);
        *reinterpret_cast<float4*>(&Raw[r * ROWF + c4 * 4]) = v;
        const float4 w = *reinterpret_cast<const float4*>(
            &vct[(col0 + r) * D + c4 * 4]);
        *reinterpret_cast<float4*>(&Raw[RAWSET + r * ROWF + c4 * 4]) = w;
    }
    __syncthreads();

    // ---- phase 2: repack triples to registers + pinned s (FROZEN) ----
    float rx0[16], rx1[16], rx2[16], rs[16];
#pragma unroll
    for (int it = 0; it < 16; ++it) {
        int task = lane + 64 * it;            // 0..1023
        int set = task >> 9;
        int rk = task & 511;
        int r = rk & 31, k = rk >> 5;
        int base = set * RAWSET + r * ROWF + 3 * k;
        float x0 = Raw[base + 0];
        float x1 = Raw[base + 1];
        float x2 = Raw[base + 2];
        float q0 = x0 * x0, q1 = x1 * x1, q2 = x2 * x2;
        asm volatile("" : "+v"(q0), "+v"(q1), "+v"(q2));
        float s02 = q0 + q2;
        asm volatile("" : "+v"(s02));
        rs[it] = s02 + q1;                    // (q0+q2)+q1, pinned plain
        rx0[it] = x0; rx1[it] = x1; rx2[it] = x2;
    }
    __syncthreads();

    // ---- phase 3: write AB chunk-major layout ----
#pragma unroll
    for (int it = 0; it < 16; ++it) {
        int task = lane + 64 * it;
        int set = task >> 9;
        int rk = task & 511;
        int r = rk & 31, k = rk >> 5;
        AB[set][k * TILE + r] = make_float4(rx0[it], rx1[it], rx2[it], rs[it]);
    }
    __syncthreads();

    const int tx = lane & 7;      // cols tx + 8j, j<4
    const int ty = lane >> 3;     // rows ty + 8i, i<4

    float G[4][4], Pd[4][4];
#pragma unroll
    for (int i = 0; i < 4; ++i)
#pragma unroll
        for (int j = 0; j < 4; ++j) { G[i][j] = 0.0f; Pd[i][j] = 1.0f; }

#pragma unroll
    for (int k = K - 1; k >= 0; --k) {
        float4 a[4], b[4];
#pragma unroll
        for (int i = 0; i < 4; ++i) a[i] = AB[0][k * TILE + ty + 8 * i];
#pragma unroll
        for (int j = 0; j < 4; ++j) b[j] = AB[1][k * TILE + tx + 8 * j];
#pragma unroll
        for (int i = 0; i < 4; ++i)
#pragma unroll
            for (int j = 0; j < 4; ++j) {
                // FROZEN distance path
                float g = __builtin_fmaf(a[i].z, b[j].z,
                          __builtin_fmaf(a[i].y, b[j].y, a[i].x * b[j].x));
                float t1 = a[i].w + b[j].w;
                float d2 = __builtin_fmaf(-2.0f, g, t1);
                float dist = __builtin_amdgcn_sqrtf(fmaxf(d2, 0.0f));
                float den = __builtin_fmaf(t2, dist, c0);   // den-fma rewrite
                G[i][j]  = l2 * (Pd[i][j] + G[i][j]);
                Pd[i][j] = Pd[i][j] * den;
            }
    }

    // finalize
    float val[4][4];
#pragma unroll
    for (int i = 0; i < 4; ++i)
#pragma unroll
        for (int j = 0; j < 4; ++j)
            val[i][j] = 1.0f + G[i][j] * __builtin_amdgcn_rcpf(Pd[i][j]);

    // direct store
#pragma unroll
    for (int i = 0; i < 4; ++i) {
        int r = ty + 8 * i;
#pragma unroll
        for (int j = 0; j < 4; ++j)
            out[(size_t)(row0 + r) * N + (col0 + tx + 8 * j)] = val[i][j];
    }

    if (bx != by) {
        __syncthreads();   // AB dead; reuse as T
#pragma unroll
        for (int i = 0; i < 4; ++i)
#pragma unroll
            for (int j = 0; j < 4; ++j)
                T[(tx + 8 * j) * ST + (ty + 8 * i)] = val[i][j];
        __syncthreads();
#pragma unroll
        for (int i = 0; i < 4; ++i) {
            int rr = ty + 8 * i;
#pragma unroll
            for (int j = 0; j < 4; ++j) {
                int cc = tx + 8 * j;
                out[(size_t)(col0 + rr) * N + (row0 + cc)] = T[rr * ST + cc];
            }
        }
    }
}

extern "C" void kernel_launch(void* const* d_in, const int* in_sizes, int n_in,
                              void* d_out, int out_size, void* d_ws, size_t ws_size,
                              hipStream_t stream) {
    const float* vct    = (const float*)d_in[0];
    const float* posnum = (const float*)d_in[1];
    float* out          = (float*)d_out;

    volt_tri<<<NBLK, 64, 0, stream>>>(vct, posnum, out);
}

// Round 27
// 22.634 us; speedup vs baseline: 1.9327x; 1.1842x over previous
//
#include <hip/hip_runtime.h>
#include <math.h>

#define N 2048
#define D 48
#define K 16
#define TILE 32
#define NT (N / TILE)              // 64 tiles per dimension
#define NBLK (NT * (NT + 1) / 2)   // 2080 upper-triangular tiles
#define ROWF 52                    // padded raw-row floats
#define RAWSET (TILE * ROWF)

// FROZEN numerics contract (validated r18 absmax=1ulp; r26 den-fma absmax=0):
//   s = (q0 + q2) + q1 (plain, pinned); g = fma(x2,y2, fma(x1,y1, fl(x0*y0)))
//   t1 = fl(s_n + s_m); d2 = fmaf(-2,g,t1); dist = sqrt(fmax(d2,0))
//   den = fmaf(t2, dist, 1-t2)   [bit-exact vs ref per r26]
// Structure = r23 (best: 128thr, 4x2 micro, 20 waves/CU) + den-fma cut.
// Evidence: waves/CU correlates with perf (r23=20 best; r24/r26<=10 worst);
// LDS read-count does NOT (r26: -33% reads, +10% time).

__global__ __launch_bounds__(128, 4)
void volt_tri(const float* __restrict__ vct, const float* __restrict__ posnum,
              float* __restrict__ out) {
#pragma clang fp contract(off)
    __shared__ float4 AB[2][K * TILE];
    float* Raw = reinterpret_cast<float*>(AB);
    float* T   = reinterpret_cast<float*>(AB);

    const int tid = threadIdx.x;

    int t = blockIdx.x;
    int by = 0;
    while ((by + 1) * NT - ((by + 1) * by) / 2 <= t) ++by;
    const int bx = by + (t - (by * NT - (by * (by - 1)) / 2));

    const int row0 = by * TILE, col0 = bx * TILE;

    const float tau = posnum[0];
    const float lam = posnum[1];
    const float t2 = tau * tau;
    const float l2 = lam * lam;
    const float c0 = 1.0f - t2;

#pragma unroll
    for (int it = 0; it < 6; ++it) {
        int task = tid + 128 * it;
        int set = task / 384;
        int rem = task - set * 384;
        int r = rem / 12;
        int c4 = rem - r * 12;
        const float4 v = *reinterpret_cast<const float4*>(
            &vct[((set ? col0 : row0) + r) * D + c4 * 4]);
        *reinterpret_cast<float4*>(&Raw[set * RAWSET + r * ROWF + c4 * 4]) = v;
    }
    __syncthreads();

    float rx0[8], rx1[8], rx2[8], rs[8];
#pragma unroll
    for (int it = 0; it < 8; ++it) {
        int task = tid + 128 * it;
        int set = task >> 9;
        int rk = task & 511;
        int r = rk & 31, k = rk >> 5;
        int base = set * RAWSET + r * ROWF + 3 * k;
        float x0 = Raw[base + 0];
        float x1 = Raw[base + 1];
        float x2 = Raw[base + 2];
        float q0 = x0 * x0, q1 = x1 * x1, q2 = x2 * x2;
        asm volatile("" : "+v"(q0), "+v"(q1), "+v"(q2));
        float s02 = q0 + q2;
        asm volatile("" : "+v"(s02));
        rs[it] = s02 + q1;
        rx0[it] = x0; rx1[it] = x1; rx2[it] = x2;
    }
    __syncthreads();

#pragma unroll
    for (int it = 0; it < 8; ++it) {
        int task = tid + 128 * it;
        int set = task >> 9;
        int rk = task & 511;
        int r = rk & 31, k = rk >> 5;
        AB[set][k * TILE + r] = make_float4(rx0[it], rx1[it], rx2[it], rs[it]);
    }
    __syncthreads();

    const int tx = tid & 15;
    const int ty = tid >> 4;

    float G[4][2], Pd[4][2];
#pragma unroll
    for (int i = 0; i < 4; ++i)
#pragma unroll
        for (int j = 0; j < 2; ++j) { G[i][j] = 0.0f; Pd[i][j] = 1.0f; }

#pragma unroll
    for (int k = K - 1; k >= 0; --k) {
        float4 a[4], b[2];
#pragma unroll
        for (int i = 0; i < 4; ++i) a[i] = AB[0][k * TILE + ty + 8 * i];
#pragma unroll
        for (int j = 0; j < 2; ++j) b[j] = AB[1][k * TILE + tx + 16 * j];
#pragma unroll
        for (int i = 0; i < 4; ++i)
#pragma unroll
            for (int j = 0; j < 2; ++j) {
                // FROZEN distance path + bit-exact den-fma
                float g = __builtin_fmaf(a[i].z, b[j].z,
                          __builtin_fmaf(a[i].y, b[j].y, a[i].x * b[j].x));
                float t1 = a[i].w + b[j].w;
                float d2 = __builtin_fmaf(-2.0f, g, t1);
                float dist = __builtin_amdgcn_sqrtf(fmaxf(d2, 0.0f));
                float den = __builtin_fmaf(t2, dist, c0);
                G[i][j]  = l2 * (Pd[i][j] + G[i][j]);
                Pd[i][j] = Pd[i][j] * den;
            }
    }

    float val[4][2];
#pragma unroll
    for (int i = 0; i < 4; ++i)
#pragma unroll
        for (int j = 0; j < 2; ++j)
            val[i][j] = 1.0f + G[i][j] * __builtin_amdgcn_rcpf(Pd[i][j]);

#pragma unroll
    for (int i = 0; i < 4; ++i) {
        int r = ty + 8 * i;
#pragma unroll
        for (int j = 0; j < 2; ++j)
            out[(size_t)(row0 + r) * N + (col0 + tx + 16 * j)] = val[i][j];
    }

    if (bx != by) {
        __syncthreads();
#pragma unroll
        for (int i = 0; i < 4; ++i)
#pragma unroll
            for (int j = 0; j < 2; ++j)
                T[(tx + 16 * j) * 33 + (ty + 8 * i)] = val[i][j];
        __syncthreads();
#pragma unroll
        for (int i = 0; i < 4; ++i) {
            int rr = ty + 8 * i;
#pragma unroll
            for (int j = 0; j < 2; ++j) {
                int cc = tx + 16 * j;
                out[(size_t)(col0 + rr) * N + (row0 + cc)] = T[rr * 33 + cc];
            }
        }
    }
}

extern "C" void kernel_launch(void* const* d_in, const int* in_sizes, int n_in,
                              void* d_out, int out_size, void* d_ws, size_t ws_size,
                              hipStream_t stream) {
    const float* vct    = (const float*)d_in[0];
    const float* posnum = (const float*)d_in[1];
    float* out          = (float*)d_out;

    volt_tri<<<NBLK, 128, 0, stream>>>(vct, posnum, out);
}